// Round 13
// baseline (45.188 us; speedup 1.0000x reference)
//
#include <hip/hip_runtime.h>
#include <math.h>

#define EPSF 1e-6f
#define LOG2E 1.4426950408889634f

__device__ __forceinline__ float sigmoidf_(float v) { return 1.0f / (1.0f + __expf(-v)); }

// ===================== encrho: 10-col tile, grid (32, nb) =====================
// LDS (floats):
//   FLT  [0,12288)   (Phase A)   | W1 [0,4096), W2 [4096,12288), W3 [0,8192)
//   SIN  [12288,12640)  [16][22]
//   SH1  [12640,13216)  [32][18]
//   SH2  [13216,13664)  [32][14]
//   SH3T [13664,13984)  [10][32]
//   RED  [13984,15520)  [8][32][6]
//   TOT  [15520,15712)  [32][6]
//   RNG  [15712,15718)
// total 15718 floats = 62.9 KB -> 2 blocks/CU (realized: grid has 512 blocks)
#define W1OFF   0
#define W2OFF   4096
#define W3OFF   0
#define SINOFF  12288
#define SH1OFF  12640
#define SH2OFF  13216
#define SH3TOFF 13664
#define REDOFF  13984
#define TOTOFF  15520
#define RNGOFF  15712

__global__ __launch_bounds__(512, 1) void encrho_kernel(
    const float* __restrict__ x, const float* __restrict__ y,
    const float* __restrict__ xg, const float* __restrict__ enc_sigma,
    const float* __restrict__ gW, const float* __restrict__ gb,
    const float* __restrict__ w1, const float* __restrict__ b1,
    const float* __restrict__ w2, const float* __restrict__ b2,
    const float* __restrict__ w3, const float* __restrict__ b3,
    const float* __restrict__ linW, const float* __restrict__ linb,
    float* __restrict__ mu_t, float* __restrict__ stdv_t,
    int nb, int M)
{
    __shared__ __align__(16) float smem[15718];
    __shared__ int scnt[3];
    float* flt = smem;

    const int tid = threadIdx.x;
    const int b = blockIdx.y;
    const int c0 = blockIdx.x * 10;
    const int ic = tid & 31, ng = tid >> 5;   // 22 valid cols, 16 n-groups

    // ---------------- Phase A: filtered encoder over 22 cols ----------------
    {
        float sg0 = __expf(enc_sigma[0]) + EPSF;
        float sg1 = __expf(enc_sigma[1]) + EPSF;
        float sg2 = __expf(enc_sigma[2]) + EPSF;
        float e20 = -0.5f * LOG2E / (sg0 * sg0);
        float e21 = -0.5f * LOG2E / (sg1 * sg1);
        float e22 = -0.5f * LOG2E / (sg2 * sg2);

        int mg = c0 - 6 + ic;
        bool cv = (ic < 22) && (mg >= 0) && (mg < M);
        float g0 = 0, g1 = 0, g2 = 0;
        if (cv) {
            const float* gp = xg + (size_t)(b * M + mg) * 3;
            g0 = gp[0]; g1 = gp[1]; g2 = gp[2];
        }
        if (tid < 3) scnt[tid] = 0;
        if (tid < 96) {
            int c = tid >> 5;
            int icc = ic < 22 ? ic : 21;
            int col = c0 - 6 + icc;
            col = col < 0 ? 0 : (col >= M ? M - 1 : col);
            float gv = xg[(size_t)(b * M + col) * 3 + c];
            float gmn = gv, gmx = gv;
            #pragma unroll
            for (int mask = 1; mask <= 16; mask <<= 1) {
                gmn = fminf(gmn, __shfl_xor(gmn, mask, 64));
                gmx = fmaxf(gmx, __shfl_xor(gmx, mask, 64));
            }
            if (ic == 0) {
                float sgc = __expf(enc_sigma[c]) + EPSF;
                smem[RNGOFF + c] = gmn - 10.0f * sgc;
                smem[RNGOFF + 3 + c] = gmx + 10.0f * sgc;
            }
        }
        __syncthreads();
        // filter pass (per-lane LDS atomic append — R10-bench-best form)
        {
            const float* xb = x + (size_t)b * 6144;
            const float* yb = y + (size_t)b * 6144;
            #pragma unroll 1
            for (int idx = tid; idx < 6144; idx += 512) {
                float xv = xb[idx];
                int c = idx % 3;
                if (xv >= smem[RNGOFF + c] && xv <= smem[RNGOFF + 3 + c]) {
                    int p = atomicAdd(&scnt[c], 1);
                    int o = (c << 12) + (p << 1);
                    flt[o] = xv;
                    flt[o + 1] = yb[idx];
                }
            }
        }
        __syncthreads();
        if (tid < 96) {
            int c = tid >> 5;
            int cnt = scnt[c];
            int cp = (cnt + 31) & ~31;
            int p = cnt + (tid & 31);
            if (p < cp) {
                int o = (c << 12) + (p << 1);
                flt[o] = 1e30f;
                flt[o + 1] = 0.0f;
            }
        }
        __syncthreads();
        int cp0 = (scnt[0] + 31) & ~31;
        int cp1 = (scnt[1] + 31) & ~31;
        int cp2 = (scnt[2] + 31) & ~31;
        float h[6];
        {
            const float2* f = (const float2*)flt;
            float s0a = 0, s0b = 0, s1a = 0, s1b = 0;
            #pragma unroll 2
            for (int n = ng; n < cp0; n += 32) {
                float2 va = f[n], vb = f[n + 16];
                float da = va.x - g0; float wa = exp2f(e20 * da * da);
                float db = vb.x - g0; float wb = exp2f(e20 * db * db);
                s0a += wa; s1a = fmaf(va.y, wa, s1a);
                s0b += wb; s1b = fmaf(vb.y, wb, s1b);
            }
            h[0] = s0a + s0b; h[3] = s1a + s1b;
        }
        {
            const float2* f = (const float2*)flt + 2048;
            float s0a = 0, s0b = 0, s1a = 0, s1b = 0;
            #pragma unroll 2
            for (int n = ng; n < cp1; n += 32) {
                float2 va = f[n], vb = f[n + 16];
                float da = va.x - g1; float wa = exp2f(e21 * da * da);
                float db = vb.x - g1; float wb = exp2f(e21 * db * db);
                s0a += wa; s1a = fmaf(va.y, wa, s1a);
                s0b += wb; s1b = fmaf(vb.y, wb, s1b);
            }
            h[1] = s0a + s0b; h[4] = s1a + s1b;
        }
        {
            const float2* f = (const float2*)flt + 4096;
            float s0a = 0, s0b = 0, s1a = 0, s1b = 0;
            #pragma unroll 2
            for (int n = ng; n < cp2; n += 32) {
                float2 va = f[n], vb = f[n + 16];
                float da = va.x - g2; float wa = exp2f(e22 * da * da);
                float db = vb.x - g2; float wb = exp2f(e22 * db * db);
                s0a += wa; s1a = fmaf(va.y, wa, s1a);
                s0b += wb; s1b = fmaf(vb.y, wb, s1b);
            }
            h[2] = s0a + s0b; h[5] = s1a + s1b;
        }
        __syncthreads();   // flt dead; W1/W2 regions reusable
        #pragma unroll
        for (int c = 0; c < 6; c++) h[c] += __shfl_xor(h[c], 32, 64);
        int lane = tid & 63, wv = tid >> 6;
        if (lane < 32) {
            float* rp = smem + REDOFF + wv * 192 + lane * 6;
            #pragma unroll
            for (int c = 0; c < 6; c++) rp[c] = h[c];
        }
        // stage w1 and w2 into stride-8 rows (overlay freed flt)
        {
            const float4* w1v4 = (const float4*)w1;   // 640
            const float4* w2v4 = (const float4*)w2;   // 1280
            #pragma unroll 1
            for (int i4 = tid; i4 < 640; i4 += 512) {
                float4 v = w1v4[i4];
                float vv[4] = {v.x, v.y, v.z, v.w};
                #pragma unroll
                for (int j = 0; j < 4; j++) {
                    int e = 4 * i4 + j;
                    int row = e / 5;
                    smem[W1OFF + row * 8 + (e - row * 5)] = vv[j];
                }
            }
            #pragma unroll 1
            for (int i4 = tid; i4 < 1280; i4 += 512) {
                float4 v = w2v4[i4];
                float vv[4] = {v.x, v.y, v.z, v.w};
                #pragma unroll
                for (int j = 0; j < 4; j++) {
                    int e = 4 * i4 + j;
                    int row = e / 5;
                    smem[W2OFF + row * 8 + (e - row * 5)] = vv[j];
                }
            }
        }
        __syncthreads();
        if (tid < 192) {
            int ic2 = tid & 31, c = tid >> 5;
            float s = 0.0f;
            #pragma unroll
            for (int w = 0; w < 8; w++) s += smem[REDOFF + w * 192 + ic2 * 6 + c];
            smem[TOTOFF + ic2 * 6 + c] = s;
        }
        __syncthreads();
        {
            int j = tid >> 5, ic2 = tid & 31;
            if (ic2 < 22) {
                int mg2 = c0 - 6 + ic2;
                float v = 0.0f;
                if (mg2 >= 0 && mg2 < M) {
                    const float* tp = smem + TOTOFF + ic2 * 6;
                    float cat[6];
                    #pragma unroll
                    for (int c = 0; c < 3; c++) {
                        cat[c] = tp[c];
                        cat[3 + c] = tp[3 + c] / (tp[c] + EPSF);
                    }
                    float r = gb[j];
                    #pragma unroll
                    for (int i = 0; i < 6; i++) r = fmaf(cat[i], gW[i * 16 + j], r);
                    v = sigmoidf_(r);
                }
                smem[SINOFF + j * 22 + ic2] = v;
            }
        }
    }
    __syncthreads();

    // ---------------- Phase B: rho CNN (scalar-read convs) + head ----------------
    {
        int o = tid >> 4, q0 = tid & 15;
        // conv1: 18 cols (global c0-4+q); q = q0 (+ q0+16 if q0<2)
        {
            float a0 = b1[o], a1 = a0;
            bool two = (q0 < 2);
            #pragma unroll 2
            for (int i = 0; i < 16; i++) {
                const float* wp = smem + W1OFF + (o * 16 + i) * 8;
                float u0 = wp[0], u1 = wp[1], u2 = wp[2], u3 = wp[3], u4 = wp[4];
                const float* ip = smem + SINOFF + i * 22;
                a0 = fmaf(ip[q0], u0, a0);     a0 = fmaf(ip[q0+1], u1, a0);
                a0 = fmaf(ip[q0+2], u2, a0);   a0 = fmaf(ip[q0+3], u3, a0);
                a0 = fmaf(ip[q0+4], u4, a0);
                if (two) {
                    a1 = fmaf(ip[q0+16], u0, a1);  a1 = fmaf(ip[q0+17], u1, a1);
                    a1 = fmaf(ip[q0+18], u2, a1);  a1 = fmaf(ip[q0+19], u3, a1);
                    a1 = fmaf(ip[q0+20], u4, a1);
                }
            }
            int g0c = c0 - 4 + q0, g1c = g0c + 16;
            smem[SH1OFF + o * 18 + q0] = (g0c >= 0 && g0c < M) ? fmaxf(a0, 0.f) : 0.f;
            if (two) smem[SH1OFF + o * 18 + q0 + 16] = (g1c >= 0 && g1c < M) ? fmaxf(a1, 0.f) : 0.f;
        }
        __syncthreads();
        // w3 early-load: global -> regs (LDS write deferred past conv2)
        float4 wreg0, wreg1, wreg2;
        {
            const float4* w3v = (const float4*)w3;   // 1280
            wreg0 = w3v[tid];
            wreg1 = w3v[tid + 512];
            if (tid < 256) wreg2 = w3v[tid + 1024];
        }
        // conv2: 14 cols (global c0-2+q0), q0 < 14
        if (q0 < 14) {
            float a0 = b2[o];
            #pragma unroll 2
            for (int i = 0; i < 32; i++) {
                const float* wp = smem + W2OFF + (o * 32 + i) * 8;
                float u0 = wp[0], u1 = wp[1], u2 = wp[2], u3 = wp[3], u4 = wp[4];
                const float* ip = smem + SH1OFF + i * 18;
                a0 = fmaf(ip[q0], u0, a0);     a0 = fmaf(ip[q0+1], u1, a0);
                a0 = fmaf(ip[q0+2], u2, a0);   a0 = fmaf(ip[q0+3], u3, a0);
                a0 = fmaf(ip[q0+4], u4, a0);
            }
            int g0c = c0 - 2 + q0;
            smem[SH2OFF + o * 14 + q0] = (g0c >= 0 && g0c < M) ? fmaxf(a0, 0.f) : 0.f;
        }
        __syncthreads();   // conv2 done reading W2; W1+W2 dead
        // w3 LDS write phase (race-free)
        {
            float vv0[4] = {wreg0.x, wreg0.y, wreg0.z, wreg0.w};
            #pragma unroll
            for (int j = 0; j < 4; j++) {
                int e = 4 * tid + j;
                int row = e / 5;
                smem[W3OFF + row * 8 + (e - row * 5)] = vv0[j];
            }
            float vv1[4] = {wreg1.x, wreg1.y, wreg1.z, wreg1.w};
            #pragma unroll
            for (int j = 0; j < 4; j++) {
                int e = 4 * (tid + 512) + j;
                int row = e / 5;
                smem[W3OFF + row * 8 + (e - row * 5)] = vv1[j];
            }
            if (tid < 256) {
                float vv2[4] = {wreg2.x, wreg2.y, wreg2.z, wreg2.w};
                #pragma unroll
                for (int j = 0; j < 4; j++) {
                    int e = 4 * (tid + 1024) + j;
                    int row = e / 5;
                    smem[W3OFF + row * 8 + (e - row * 5)] = vv2[j];
                }
            }
        }
        __syncthreads();
        // conv3: 10 cols (global c0+q0), q0 < 10; transposed out
        if (q0 < 10) {
            float a0 = b3[o];
            #pragma unroll 2
            for (int i = 0; i < 32; i++) {
                const float* wp = smem + W3OFF + (o * 32 + i) * 8;
                float u0 = wp[0], u1 = wp[1], u2 = wp[2], u3 = wp[3], u4 = wp[4];
                const float* ip = smem + SH2OFF + i * 14;
                a0 = fmaf(ip[q0], u0, a0);     a0 = fmaf(ip[q0+1], u1, a0);
                a0 = fmaf(ip[q0+2], u2, a0);   a0 = fmaf(ip[q0+3], u3, a0);
                a0 = fmaf(ip[q0+4], u4, a0);
            }
            smem[SH3TOFF + q0 * 32 + o] = a0;
        }
        __syncthreads();
        // head: 10 cols x 30 outs = 300; transposed planes (b, k, M)
        if (tid < 300) {
            int q = tid / 30, j = tid - (tid / 30) * 30;
            int m = c0 + q;
            if (m < M) {
                const float* hp = smem + SH3TOFF + q * 32;
                float v = linb[j];
                #pragma unroll
                for (int o4 = 0; o4 < 8; o4++) {
                    float4 h4 = *(const float4*)(hp + o4 * 4);
                    const float* lw = linW + o4 * 4 * 30 + j;
                    v = fmaf(h4.x, lw[0], v);
                    v = fmaf(h4.y, lw[30], v);
                    v = fmaf(h4.z, lw[60], v);
                    v = fmaf(h4.w, lw[90], v);
                }
                if (j < 15) mu_t[((size_t)b * 15 + j) * M + m] = v;
                else        stdv_t[((size_t)b * 15 + (j - 15)) * M + m] = 0.1f + 0.9f * sigmoidf_(v);
            }
        }
    }
}

// ---------------- K2: windowed interpolation, coalesced transposed planes ----------------
__global__ __launch_bounds__(256, 4) void final_kernel(
    const float* __restrict__ x_out, const float* __restrict__ xg,
    const float* __restrict__ int_sigma, const float* __restrict__ eps,
    const float* __restrict__ mu_t, const float* __restrict__ stdv_t,
    const float* __restrict__ loW, const float* __restrict__ lob,
    float* __restrict__ out, int nb, int ntar, int M)
{
    __shared__ float AB[8][30];
    int b = blockIdx.y;
    int tt = blockIdx.x * 8;
    int tid = threadIdx.x;
    int mg = tid & 31, ti = tid >> 5;
    int t = tt + ti;
    bool tv = (t < ntar);
    float xt[3];
    #pragma unroll
    for (int c = 0; c < 3; c++) xt[c] = tv ? x_out[((size_t)b * ntar + t) * 3 + c] : 0.0f;
    float k2[15], Wc[3] = {0, 0, 0};
    #pragma unroll
    for (int k = 0; k < 15; k++) {
        float isc = __expf(int_sigma[k]) + EPSF;
        k2[k] = -0.5f * LOG2E / (isc * isc);
        Wc[k % 3] = fmaxf(Wc[k % 3], 10.0f * isc);
    }
    float gg0 = xg[(size_t)b * M * 3];
    float ggL = xg[((size_t)b * M + (M - 1)) * 3];
    float Dx = (ggL - gg0) / (float)(M - 1);
    float invDx = 1.0f / Dx;
    float A[15], B[15];
    #pragma unroll
    for (int k = 0; k < 15; k++) { A[k] = 0.0f; B[k] = 0.0f; }
    #pragma unroll
    for (int c = 0; c < 3; c++) {
        float xtc = xt[c];
        int lo = (int)floorf((xtc - Wc[c] - gg0) * invDx) - 1;
        int hi = (int)ceilf((xtc + Wc[c] - gg0) * invDx) + 1;
        lo = lo < 0 ? 0 : lo;
        hi = hi > M - 1 ? M - 1 : hi;
        const float* pm0 = mu_t + ((size_t)b * 15 + c) * M;
        const float* pm1 = pm0 + 3 * M;
        const float* pm2 = pm0 + 6 * M;
        const float* pm3 = pm0 + 9 * M;
        const float* pm4 = pm0 + 12 * M;
        const float* ps0 = stdv_t + ((size_t)b * 15 + c) * M;
        const float* ps1 = ps0 + 3 * M;
        const float* ps2 = ps0 + 6 * M;
        const float* ps3 = ps0 + 9 * M;
        const float* ps4 = ps0 + 12 * M;
        #pragma unroll 1
        for (int m = lo + mg; m <= hi; m += 32) {
            float d = (gg0 + m * Dx) - xtc;
            float d2 = d * d;
            float w0 = exp2f(k2[c] * d2);
            float w1v = exp2f(k2[c + 3] * d2);
            float w2v = exp2f(k2[c + 6] * d2);
            float w3v = exp2f(k2[c + 9] * d2);
            float w4v = exp2f(k2[c + 12] * d2);
            A[c]      = fmaf(pm0[m], w0, A[c]);       B[c]      = fmaf(ps0[m], w0, B[c]);
            A[c + 3]  = fmaf(pm1[m], w1v, A[c + 3]);  B[c + 3]  = fmaf(ps1[m], w1v, B[c + 3]);
            A[c + 6]  = fmaf(pm2[m], w2v, A[c + 6]);  B[c + 6]  = fmaf(ps2[m], w2v, B[c + 6]);
            A[c + 9]  = fmaf(pm3[m], w3v, A[c + 9]);  B[c + 9]  = fmaf(ps3[m], w3v, B[c + 9]);
            A[c + 12] = fmaf(pm4[m], w4v, A[c + 12]); B[c + 12] = fmaf(ps4[m], w4v, B[c + 12]);
        }
    }
    #pragma unroll
    for (int mask = 1; mask <= 16; mask <<= 1) {
        #pragma unroll
        for (int k = 0; k < 15; k++) {
            A[k] += __shfl_xor(A[k], mask, 64);
            B[k] += __shfl_xor(B[k], mask, 64);
        }
    }
    if (mg == 0) {
        #pragma unroll
        for (int k = 0; k < 15; k++) { AB[ti][k] = A[k]; AB[ti][15 + k] = B[k]; }
    }
    __syncthreads();
    if (tid < 192) {
        int t2 = tid / 24;
        int rem = tid - t2 * 24;
        int s = rem / 6, j = rem - s * 6;
        int tg = tt + t2;
        if (tg < ntar) {
            float val = lob[j];
            const float* ep = eps + ((size_t)s * nb + b) * 15;
            #pragma unroll
            for (int k = 0; k < 15; k++) {
                float h = fmaf(ep[k], AB[t2][15 + k], AB[t2][k]);
                val = fmaf(h, loW[k * 6 + j], val);
            }
            if (j >= 3) val = fmaxf(val, 0.0f) + log1pf(__expf(-fabsf(val)));  // softplus
            out[(((size_t)s * nb + b) * ntar + tg) * 6 + j] = val;
        }
    }
}

// =====================================================================
// Fallback path (generic shapes) — head writes transposed planes
// =====================================================================

__global__ __launch_bounds__(1024) void enc_kernel_g(
    const float* __restrict__ x, const float* __restrict__ y,
    const float* __restrict__ xg, const float* __restrict__ enc_sigma,
    const float* __restrict__ gW, const float* __restrict__ gb,
    float* __restrict__ rep_s, int nb, int npts, int M)
{
    __shared__ float sx[6144];
    __shared__ float sy[6144];
    __shared__ float red[16][8][6];
    __shared__ float tot[8][6];
    int b = blockIdx.y;
    int mt = blockIdx.x * 8;
    int tid = threadIdx.x;
    int n3 = npts * 3;
    if (n3 > 6144) n3 = 6144;
    for (int i = tid; i < n3; i += 1024) {
        sx[i] = x[(size_t)b * npts * 3 + i];
        sy[i] = y[(size_t)b * npts * 3 + i];
    }
    int npts_l = n3 / 3;
    int mi = tid & 7, ng = tid >> 3;
    int m = mt + mi;
    bool mv = (m < M);
    float e1[3], g[3];
    for (int c = 0; c < 3; c++) {
        float inv = 1.0f / (__expf(enc_sigma[c]) + EPSF);
        e1[c] = -0.5f * inv * inv;
    }
    for (int c = 0; c < 3; c++) g[c] = mv ? xg[(size_t)(b * M + m) * 3 + c] : 0.0f;
    __syncthreads();
    float h0[3] = {0,0,0}, h1[3] = {0,0,0};
    for (int n = ng; n < npts_l; n += 128) {
        for (int c = 0; c < 3; c++) {
            float d = sx[n * 3 + c] - g[c];
            float w = __expf(e1[c] * d * d);
            h0[c] += w;
            h1[c] = fmaf(sy[n * 3 + c], w, h1[c]);
        }
    }
    for (int mask = 8; mask <= 32; mask <<= 1) {
        for (int c = 0; c < 3; c++) {
            h0[c] += __shfl_xor(h0[c], mask, 64);
            h1[c] += __shfl_xor(h1[c], mask, 64);
        }
    }
    int lane = tid & 63, wv = tid >> 6;
    if (lane < 8) {
        for (int c = 0; c < 3; c++) { red[wv][lane][c] = h0[c]; red[wv][lane][3 + c] = h1[c]; }
    }
    __syncthreads();
    if (tid < 48) {
        int mi2 = tid & 7, c2 = tid >> 3;
        float s = 0.0f;
        for (int k = 0; k < 16; k++) s += red[k][mi2][c2];
        tot[mi2][c2] = s;
    }
    __syncthreads();
    if (tid < 128) {
        int mi2 = tid & 7, j = tid >> 3;
        int m2 = mt + mi2;
        if (m2 < M) {
            float cat[6];
            for (int c = 0; c < 3; c++) {
                cat[c] = tot[mi2][c];
                cat[3 + c] = tot[mi2][3 + c] / (tot[mi2][c] + EPSF);
            }
            float r = gb[j];
            for (int i = 0; i < 6; i++) r = fmaf(cat[i], gW[i * 16 + j], r);
            rep_s[((size_t)b * 16 + j) * M + m2] = sigmoidf_(r);
        }
    }
}

__global__ __launch_bounds__(256) void rho_kernel_g(
    const float* __restrict__ rep_s,
    const float* __restrict__ w1, const float* __restrict__ b1,
    const float* __restrict__ w2, const float* __restrict__ b2,
    const float* __restrict__ w3, const float* __restrict__ b3,
    const float* __restrict__ linW, const float* __restrict__ linb,
    float* __restrict__ mu_t, float* __restrict__ stdv_t,
    int nb, int M)
{
    __shared__ float sWA[5152];
    __shared__ float sWB[5152];
    __shared__ float sIn[16][20];
    __shared__ float sH1[32][16];
    __shared__ float sH2[32][12];
    __shared__ float sH3[32][8];
    int b = blockIdx.y;
    int t0 = blockIdx.x * 8;
    int tid = threadIdx.x;
    {
        const float4* w1v = (const float4*)w1;
        const float4* w2v = (const float4*)w2;
        for (int i4 = tid; i4 < 640; i4 += 256) {
            float4 v = w1v[i4];
            float vv[4] = {v.x, v.y, v.z, v.w};
            for (int j = 0; j < 4; j++) {
                int e = 4 * i4 + j;
                sWA[(e / 80) * 81 + e % 80] = vv[j];
            }
        }
        for (int i4 = tid; i4 < 1280; i4 += 256) {
            float4 v = w2v[i4];
            float vv[4] = {v.x, v.y, v.z, v.w};
            for (int j = 0; j < 4; j++) {
                int e = 4 * i4 + j;
                sWB[(e / 160) * 161 + e % 160] = vv[j];
            }
        }
        for (int idx = tid; idx < 16 * 20; idx += 256) {
            int i = idx / 20, q = idx % 20;
            int mg = t0 - 6 + q;
            sIn[i][q] = (mg >= 0 && mg < M) ? rep_s[((size_t)b * 16 + i) * M + mg] : 0.0f;
        }
    }
    __syncthreads();
    int o = tid >> 3, q0 = tid & 7;
    {
        float a0 = b1[o], a1 = a0;
        #pragma unroll 2
        for (int i = 0; i < 16; i++) {
            const float* wp = sWA + o * 81 + i * 5;
            float u0 = wp[0], u1 = wp[1], u2 = wp[2], u3 = wp[3], u4 = wp[4];
            const float* ip = &sIn[i][0];
            a0 = fmaf(ip[q0], u0, a0);      a0 = fmaf(ip[q0+1], u1, a0);
            a0 = fmaf(ip[q0+2], u2, a0);    a0 = fmaf(ip[q0+3], u3, a0);
            a0 = fmaf(ip[q0+4], u4, a0);
            a1 = fmaf(ip[q0+8], u0, a1);    a1 = fmaf(ip[q0+9], u1, a1);
            a1 = fmaf(ip[q0+10], u2, a1);   a1 = fmaf(ip[q0+11], u3, a1);
            a1 = fmaf(ip[q0+12], u4, a1);
        }
        int g0 = t0 - 4 + q0, g1 = g0 + 8;
        sH1[o][q0]     = (g0 >= 0 && g0 < M) ? fmaxf(a0, 0.0f) : 0.0f;
        sH1[o][q0 + 8] = (g1 >= 0 && g1 < M) ? fmaxf(a1, 0.0f) : 0.0f;
    }
    __syncthreads();
    float4 wreg[5];
    {
        const float4* w3v = (const float4*)w3;
        for (int h = 0; h < 5; h++) wreg[h] = w3v[tid + 256 * h];
    }
    {
        float a0 = b2[o], a1 = a0;
        bool second = (q0 < 4);
        #pragma unroll 2
        for (int i = 0; i < 32; i++) {
            const float* wp = sWB + o * 161 + i * 5;
            float u0 = wp[0], u1 = wp[1], u2 = wp[2], u3 = wp[3], u4 = wp[4];
            const float* ip = &sH1[i][0];
            a0 = fmaf(ip[q0], u0, a0);      a0 = fmaf(ip[q0+1], u1, a0);
            a0 = fmaf(ip[q0+2], u2, a0);    a0 = fmaf(ip[q0+3], u3, a0);
            a0 = fmaf(ip[q0+4], u4, a0);
            if (second) {
                a1 = fmaf(ip[q0+8], u0, a1);    a1 = fmaf(ip[q0+9], u1, a1);
                a1 = fmaf(ip[q0+10], u2, a1);   a1 = fmaf(ip[q0+11], u3, a1);
                a1 = fmaf(ip[q0+12], u4, a1);
            }
        }
        int g0 = t0 - 2 + q0, g1 = g0 + 8;
        sH2[o][q0] = (g0 >= 0 && g0 < M) ? fmaxf(a0, 0.0f) : 0.0f;
        if (second) sH2[o][q0 + 8] = (g1 >= 0 && g1 < M) ? fmaxf(a1, 0.0f) : 0.0f;
    }
    __syncthreads();
    for (int h = 0; h < 5; h++) {
        float vv[4] = {wreg[h].x, wreg[h].y, wreg[h].z, wreg[h].w};
        for (int j = 0; j < 4; j++) {
            int e = 4 * (tid + 256 * h) + j;
            sWA[(e / 160) * 161 + e % 160] = vv[j];
        }
    }
    __syncthreads();
    {
        float a0 = b3[o];
        #pragma unroll 2
        for (int i = 0; i < 32; i++) {
            const float* wp = sWA + o * 161 + i * 5;
            float u0 = wp[0], u1 = wp[1], u2 = wp[2], u3 = wp[3], u4 = wp[4];
            const float* ip = &sH2[i][0];
            a0 = fmaf(ip[q0], u0, a0);      a0 = fmaf(ip[q0+1], u1, a0);
            a0 = fmaf(ip[q0+2], u2, a0);    a0 = fmaf(ip[q0+3], u3, a0);
            a0 = fmaf(ip[q0+4], u4, a0);
        }
        sH3[o][q0] = a0;
    }
    __syncthreads();
    if (tid < 240) {
        int q = tid / 30, j = tid % 30;
        int m = t0 + q;
        if (m < M) {
            float v = linb[j];
            #pragma unroll 8
            for (int oo = 0; oo < 32; oo++) v = fmaf(sH3[oo][q], linW[oo * 30 + j], v);
            if (j < 15) mu_t[((size_t)b * 15 + j) * M + m] = v;
            else        stdv_t[((size_t)b * 15 + (j - 15)) * M + m] = 0.1f + 0.9f * sigmoidf_(v);
        }
    }
}

extern "C" void kernel_launch(void* const* d_in, const int* in_sizes, int n_in,
                              void* d_out, int out_size, void* d_ws, size_t ws_size,
                              hipStream_t stream)
{
    const float* x         = (const float*)d_in[0];
    const float* y         = (const float*)d_in[1];
    const float* x_out     = (const float*)d_in[2];
    const float* x_grid    = (const float*)d_in[3];
    const float* eps_noise = (const float*)d_in[4];
    const float* enc_sigma = (const float*)d_in[5];
    const float* gW        = (const float*)d_in[6];
    const float* gb        = (const float*)d_in[7];
    const float* w1        = (const float*)d_in[8];
    const float* b1        = (const float*)d_in[9];
    const float* w2        = (const float*)d_in[10];
    const float* b2        = (const float*)d_in[11];
    const float* w3        = (const float*)d_in[12];
    const float* b3        = (const float*)d_in[13];
    const float* linW      = (const float*)d_in[14];
    const float* linb      = (const float*)d_in[15];
    const float* int_sigma = (const float*)d_in[16];
    const float* loW       = (const float*)d_in[17];
    const float* lob       = (const float*)d_in[18];
    float* out = (float*)d_out;

    const int NS = 4, C = 3, NBASIS = 5;
    int nb   = in_sizes[4] / (NS * C * NBASIS);       // eps_noise: (NS, nb, 15)
    int npts = in_sizes[0] / (nb * C);
    int ntar = in_sizes[2] / (nb * C);
    int M    = in_sizes[3] / (nb * C);

    float* mu_t   = (float*)d_ws;                      // (nb, 15, M) planes
    float* stdv_t = mu_t + (size_t)nb * 15 * M;        // (nb, 15, M)

    bool fast = (npts == 2048 && M <= 320);
    if (fast) {
        int tiles = (M + 9) / 10;
        encrho_kernel<<<dim3(tiles, nb), 512, 0, stream>>>(
            x, y, x_grid, enc_sigma, gW, gb,
            w1, b1, w2, b2, w3, b3, linW, linb, mu_t, stdv_t, nb, M);
    } else {
        float* rep_s = stdv_t + (size_t)nb * 15 * M;   // (nb, 16, M)
        enc_kernel_g<<<dim3((M + 7) / 8, nb), 1024, 0, stream>>>(
            x, y, x_grid, enc_sigma, gW, gb, rep_s, nb, npts, M);
        rho_kernel_g<<<dim3((M + 7) / 8, nb), 256, 0, stream>>>(
            rep_s, w1, b1, w2, b2, w3, b3, linW, linb, mu_t, stdv_t, nb, M);
    }
    final_kernel<<<dim3((ntar + 7) / 8, nb), 256, 0, stream>>>(
        x_out, x_grid, int_sigma, eps_noise, mu_t, stdv_t, loW, lob, out, nb, ntar, M);
}

// Round 14
// 37.673 us; speedup vs baseline: 1.1995x; 1.1995x over previous
//
#include <hip/hip_runtime.h>
#include <math.h>

#define EPSF 1e-6f
#define LOG2E 1.4426950408889634f
#define NSIG 6.5f

__device__ __forceinline__ float sigmoidf_(float v) { return 1.0f / (1.0f + __expf(-v)); }

// =====================================================================
// K1: fused enc + rho per 20-col tile, Gaussian-support prefilter.
// grid (16, nb), 512 threads. LDS UNION (Phase A flt overlays Phase B
// weight/tile regions) -> 59.4 KB. (R9 configuration — best measured.)
// =====================================================================
__global__ __launch_bounds__(512, 1) void encrho_kernel(
    const float* __restrict__ x, const float* __restrict__ y,
    const float* __restrict__ xg, const float* __restrict__ enc_sigma,
    const float* __restrict__ gW, const float* __restrict__ gb,
    const float* __restrict__ w1, const float* __restrict__ b1,
    const float* __restrict__ w2, const float* __restrict__ b2,
    const float* __restrict__ w3, const float* __restrict__ b3,
    const float* __restrict__ linW, const float* __restrict__ linb,
    float* __restrict__ mu, float* __restrict__ stdv,
    int nb, int M)
{
    __shared__ __align__(16) float smem[14856];
    float* sWA = smem;
    float* sWB = smem + 5152;
    float* sH1 = smem + 10304;
    float* sH2 = smem + 11200;
    float* sH3 = smem + 11968;
    float* sIn = smem + 12608;
    float* flt = smem;               // [3][2048] float2 (Phase A only)
    float* red = smem + 13120;
    float* tot = smem + 14656;
    float* sRange = smem + 14848;
    __shared__ int scnt[3];
    __shared__ int spad[3];

    const int tid = threadIdx.x;
    const int b = blockIdx.y;
    const int c0 = blockIdx.x * 20;
    const int ic = tid & 31, ng = tid >> 5;

    // ---------------- Phase A: filtered encoder over 32 cols ----------------
    {
        float sg0 = __expf(enc_sigma[0]) + EPSF;
        float sg1 = __expf(enc_sigma[1]) + EPSF;
        float sg2 = __expf(enc_sigma[2]) + EPSF;
        float e20 = -0.5f * LOG2E / (sg0 * sg0);
        float e21 = -0.5f * LOG2E / (sg1 * sg1);
        float e22 = -0.5f * LOG2E / (sg2 * sg2);

        int mg = c0 - 6 + ic;
        bool cv = (mg >= 0 && mg < M);
        float g0 = 0, g1 = 0, g2 = 0;
        if (cv) {
            const float* gp = xg + (size_t)(b * M + mg) * 3;
            g0 = gp[0]; g1 = gp[1]; g2 = gp[2];
        }
        if (tid < 3) scnt[tid] = 0;
        if (tid < 96) {
            int c = tid >> 5;
            int col = c0 - 6 + ic;
            col = col < 0 ? 0 : (col >= M ? M - 1 : col);
            float gv = xg[(size_t)(b * M + col) * 3 + c];
            float gmn = gv, gmx = gv;
            #pragma unroll
            for (int mask = 1; mask <= 16; mask <<= 1) {
                gmn = fminf(gmn, __shfl_xor(gmn, mask, 64));
                gmx = fmaxf(gmx, __shfl_xor(gmx, mask, 64));
            }
            if (ic == 0) {
                float sgc = __expf(enc_sigma[c]) + EPSF;
                sRange[c] = gmn - NSIG * sgc;
                sRange[3 + c] = gmx + NSIG * sgc;
            }
        }
        __syncthreads();
        // filter pass
        {
            const float* xb = x + (size_t)b * 6144;
            const float* yb = y + (size_t)b * 6144;
            #pragma unroll 1
            for (int idx = tid; idx < 6144; idx += 512) {
                float xv = xb[idx];
                int c = idx % 3;
                if (xv >= sRange[c] && xv <= sRange[3 + c]) {
                    int p = atomicAdd(&scnt[c], 1);
                    int o = (c << 12) + (p << 1);
                    flt[o] = xv;
                    flt[o + 1] = yb[idx];
                }
            }
        }
        __syncthreads();
        if (tid < 3) spad[tid] = (scnt[tid] + 31) & ~31;
        __syncthreads();
        #pragma unroll
        for (int c = 0; c < 3; c++) {
            int cnt = scnt[c], cp = spad[c];
            for (int p = cnt + tid; p < cp; p += 512) {
                int o = (c << 12) + (p << 1);
                flt[o] = 1e30f;
                flt[o + 1] = 0.0f;
            }
        }
        __syncthreads();
        // main loops: per channel, dual accumulator pairs (n, n+16)
        float h[6];
        {
            const float2* f = (const float2*)flt;
            int cp = spad[0];
            float s0a = 0, s0b = 0, s1a = 0, s1b = 0;
            #pragma unroll 2
            for (int n = ng; n < cp; n += 32) {
                float2 va = f[n], vb = f[n + 16];
                float da = va.x - g0; float wa = exp2f(e20 * da * da);
                float db = vb.x - g0; float wb = exp2f(e20 * db * db);
                s0a += wa; s1a = fmaf(va.y, wa, s1a);
                s0b += wb; s1b = fmaf(vb.y, wb, s1b);
            }
            h[0] = s0a + s0b; h[3] = s1a + s1b;
        }
        {
            const float2* f = (const float2*)flt + 2048;
            int cp = spad[1];
            float s0a = 0, s0b = 0, s1a = 0, s1b = 0;
            #pragma unroll 2
            for (int n = ng; n < cp; n += 32) {
                float2 va = f[n], vb = f[n + 16];
                float da = va.x - g1; float wa = exp2f(e21 * da * da);
                float db = vb.x - g1; float wb = exp2f(e21 * db * db);
                s0a += wa; s1a = fmaf(va.y, wa, s1a);
                s0b += wb; s1b = fmaf(vb.y, wb, s1b);
            }
            h[1] = s0a + s0b; h[4] = s1a + s1b;
        }
        {
            const float2* f = (const float2*)flt + 4096;
            int cp = spad[2];
            float s0a = 0, s0b = 0, s1a = 0, s1b = 0;
            #pragma unroll 2
            for (int n = ng; n < cp; n += 32) {
                float2 va = f[n], vb = f[n + 16];
                float da = va.x - g2; float wa = exp2f(e22 * da * da);
                float db = vb.x - g2; float wb = exp2f(e22 * db * db);
                s0a += wa; s1a = fmaf(va.y, wa, s1a);
                s0b += wb; s1b = fmaf(vb.y, wb, s1b);
            }
            h[2] = s0a + s0b; h[5] = s1a + s1b;
        }
        __syncthreads();   // all flt reads done; sWA/sWB region reusable
        #pragma unroll
        for (int c = 0; c < 6; c++) h[c] += __shfl_xor(h[c], 32, 64);
        int lane = tid & 63, wv = tid >> 6;
        if (lane < 32) {
            float* rp = red + wv * 192 + lane * 6;
            #pragma unroll
            for (int c = 0; c < 6; c++) rp[c] = h[c];
        }
        // stage w1 (pad 81) and w2 (pad 161) into freed flt region
        {
            const float4* w1v4 = (const float4*)w1;   // 640
            const float4* w2v4 = (const float4*)w2;   // 1280
            #pragma unroll 1
            for (int i4 = tid; i4 < 640; i4 += 512) {
                float4 v = w1v4[i4];
                float vv[4] = {v.x, v.y, v.z, v.w};
                #pragma unroll
                for (int j = 0; j < 4; j++) {
                    int e = 4 * i4 + j;
                    sWA[(e / 80) * 81 + e % 80] = vv[j];
                }
            }
            #pragma unroll 1
            for (int i4 = tid; i4 < 1280; i4 += 512) {
                float4 v = w2v4[i4];
                float vv[4] = {v.x, v.y, v.z, v.w};
                #pragma unroll
                for (int j = 0; j < 4; j++) {
                    int e = 4 * i4 + j;
                    sWB[(e / 160) * 161 + e % 160] = vv[j];
                }
            }
        }
        __syncthreads();
        if (tid < 192) {
            int ic2 = tid & 31, c = tid >> 5;
            float s = 0.0f;
            #pragma unroll
            for (int w = 0; w < 8; w++) s += red[w * 192 + ic2 * 6 + c];
            tot[ic2 * 6 + c] = s;
        }
        __syncthreads();
        {
            int j = tid >> 5, ic2 = tid & 31;
            int mg2 = c0 - 6 + ic2;
            float v = 0.0f;
            if (mg2 >= 0 && mg2 < M) {
                const float* tp = tot + ic2 * 6;
                float cat[6];
                #pragma unroll
                for (int c = 0; c < 3; c++) {
                    cat[c] = tp[c];
                    cat[3 + c] = tp[3 + c] / (tp[c] + EPSF);
                }
                float r = gb[j];
                #pragma unroll
                for (int i = 0; i < 6; i++) r = fmaf(cat[i], gW[i * 16 + j], r);
                v = sigmoidf_(r);
            }
            sIn[j * 32 + ic2] = v;
        }
    }
    __syncthreads();

    // ---------------- Phase B: rho CNN + head ----------------
    {
        int o = tid >> 4, q0 = tid & 15;
        {
            float a0 = b1[o], a1 = a0;
            bool two = (q0 < 12);
            #pragma unroll 2
            for (int i = 0; i < 16; i++) {
                const float* wp = sWA + o * 81 + i * 5;
                float u0 = wp[0], u1 = wp[1], u2 = wp[2], u3 = wp[3], u4 = wp[4];
                const float* ip = sIn + i * 32;
                a0 = fmaf(ip[q0], u0, a0);     a0 = fmaf(ip[q0+1], u1, a0);
                a0 = fmaf(ip[q0+2], u2, a0);   a0 = fmaf(ip[q0+3], u3, a0);
                a0 = fmaf(ip[q0+4], u4, a0);
                if (two) {
                    a1 = fmaf(ip[q0+16], u0, a1);  a1 = fmaf(ip[q0+17], u1, a1);
                    a1 = fmaf(ip[q0+18], u2, a1);  a1 = fmaf(ip[q0+19], u3, a1);
                    a1 = fmaf(ip[q0+20], u4, a1);
                }
            }
            int g0c = c0 - 4 + q0, g1c = g0c + 16;
            sH1[o * 28 + q0] = (g0c >= 0 && g0c < M) ? fmaxf(a0, 0.0f) : 0.0f;
            if (two) sH1[o * 28 + q0 + 16] = (g1c >= 0 && g1c < M) ? fmaxf(a1, 0.0f) : 0.0f;
        }
        __syncthreads();
        float4 wreg0, wreg1, wreg2;
        {
            const float4* w3v = (const float4*)w3;   // 1280
            wreg0 = w3v[tid];
            wreg1 = w3v[tid + 512];
            if (tid < 256) wreg2 = w3v[tid + 1024];
        }
        {
            float a0 = b2[o], a1 = a0;
            bool two = (q0 < 8);
            #pragma unroll 2
            for (int i = 0; i < 32; i++) {
                const float* wp = sWB + o * 161 + i * 5;
                float u0 = wp[0], u1 = wp[1], u2 = wp[2], u3 = wp[3], u4 = wp[4];
                const float* ip = sH1 + i * 28;
                a0 = fmaf(ip[q0], u0, a0);     a0 = fmaf(ip[q0+1], u1, a0);
                a0 = fmaf(ip[q0+2], u2, a0);   a0 = fmaf(ip[q0+3], u3, a0);
                a0 = fmaf(ip[q0+4], u4, a0);
                if (two) {
                    a1 = fmaf(ip[q0+16], u0, a1);  a1 = fmaf(ip[q0+17], u1, a1);
                    a1 = fmaf(ip[q0+18], u2, a1);  a1 = fmaf(ip[q0+19], u3, a1);
                    a1 = fmaf(ip[q0+20], u4, a1);
                }
            }
            int g0c = c0 - 2 + q0, g1c = g0c + 16;
            sH2[o * 24 + q0] = (g0c >= 0 && g0c < M) ? fmaxf(a0, 0.0f) : 0.0f;
            if (two) sH2[o * 24 + q0 + 16] = (g1c >= 0 && g1c < M) ? fmaxf(a1, 0.0f) : 0.0f;
        }
        __syncthreads();   // conv2 done reading sWB; sWA (conv1 w1) also dead
        {
            float vv0[4] = {wreg0.x, wreg0.y, wreg0.z, wreg0.w};
            #pragma unroll
            for (int j = 0; j < 4; j++) {
                int e = 4 * tid + j;
                sWA[(e / 160) * 161 + e % 160] = vv0[j];
            }
            float vv1[4] = {wreg1.x, wreg1.y, wreg1.z, wreg1.w};
            #pragma unroll
            for (int j = 0; j < 4; j++) {
                int e = 4 * (tid + 512) + j;
                sWA[(e / 160) * 161 + e % 160] = vv1[j];
            }
            if (tid < 256) {
                float vv2[4] = {wreg2.x, wreg2.y, wreg2.z, wreg2.w};
                #pragma unroll
                for (int j = 0; j < 4; j++) {
                    int e = 4 * (tid + 1024) + j;
                    sWA[(e / 160) * 161 + e % 160] = vv2[j];
                }
            }
        }
        __syncthreads();
        {
            float a0 = b3[o], a1 = a0;
            bool two = (q0 < 4);
            #pragma unroll 2
            for (int i = 0; i < 32; i++) {
                const float* wp = sWA + o * 161 + i * 5;
                float u0 = wp[0], u1 = wp[1], u2 = wp[2], u3 = wp[3], u4 = wp[4];
                const float* ip = sH2 + i * 24;
                a0 = fmaf(ip[q0], u0, a0);     a0 = fmaf(ip[q0+1], u1, a0);
                a0 = fmaf(ip[q0+2], u2, a0);   a0 = fmaf(ip[q0+3], u3, a0);
                a0 = fmaf(ip[q0+4], u4, a0);
                if (two) {
                    a1 = fmaf(ip[q0+16], u0, a1);  a1 = fmaf(ip[q0+17], u1, a1);
                    a1 = fmaf(ip[q0+18], u2, a1);  a1 = fmaf(ip[q0+19], u3, a1);
                    a1 = fmaf(ip[q0+20], u4, a1);
                }
            }
            sH3[o * 20 + q0] = a0;
            if (two) sH3[o * 20 + q0 + 16] = a1;
        }
        __syncthreads();
        #pragma unroll 1
        for (int idx = tid; idx < 600; idx += 512) {
            int q = idx / 30, j = idx % 30;
            int m = c0 + q;
            if (m < M) {
                float v = linb[j];
                #pragma unroll 8
                for (int oo = 0; oo < 32; oo++) v = fmaf(sH3[oo * 20 + q], linW[oo * 30 + j], v);
                if (j < 15) mu[((size_t)b * M + m) * 16 + j] = v;
                else        stdv[((size_t)b * M + m) * 16 + (j - 15)] = 0.1f + 0.9f * sigmoidf_(v);
            }
        }
    }
}

// ---------------- K2: windowed interpolation + output head ----------------
__global__ __launch_bounds__(256, 4) void final_kernel(
    const float* __restrict__ x_out, const float* __restrict__ xg,
    const float* __restrict__ int_sigma, const float* __restrict__ eps,
    const float* __restrict__ mu, const float* __restrict__ stdv,
    const float* __restrict__ loW, const float* __restrict__ lob,
    float* __restrict__ out, int nb, int ntar, int M)
{
    __shared__ float red2[4][8][30];
    __shared__ float AB[8][30];
    int b = blockIdx.y;
    int tt = blockIdx.x * 8;
    int tid = threadIdx.x;
    int ti = tid & 7, mg = tid >> 3;
    int t = tt + ti;
    bool tv = (t < ntar);
    float xt[3];
    for (int c = 0; c < 3; c++) xt[c] = tv ? x_out[((size_t)b * ntar + t) * 3 + c] : 0.0f;
    float k2[15], Wc[3] = {0, 0, 0};
    #pragma unroll
    for (int k = 0; k < 15; k++) {
        float isc = __expf(int_sigma[k]) + EPSF;
        k2[k] = -0.5f * LOG2E / (isc * isc);
        Wc[k % 3] = fmaxf(Wc[k % 3], NSIG * isc);
    }
    float gg0 = xg[(size_t)b * M * 3];
    float ggL = xg[((size_t)b * M + (M - 1)) * 3];
    float Dx = (ggL - gg0) / (float)(M - 1);
    float invDx = 1.0f / Dx;
    float A[15], B[15];
    #pragma unroll
    for (int k = 0; k < 15; k++) { A[k] = 0.0f; B[k] = 0.0f; }
    #pragma unroll
    for (int c = 0; c < 3; c++) {
        float xtc = xt[c];
        int lo = (int)floorf((xtc - Wc[c] - gg0) * invDx) - 1;
        int hi = (int)ceilf((xtc + Wc[c] - gg0) * invDx) + 1;
        lo = lo < 0 ? 0 : lo;
        hi = hi > M - 1 ? M - 1 : hi;
        #pragma unroll 1
        for (int m = lo + mg; m <= hi; m += 32) {
            float d = (gg0 + m * Dx) - xtc;
            float d2 = d * d;
            const float* mup = mu + ((size_t)b * M + m) * 16;
            const float* sdp = stdv + ((size_t)b * M + m) * 16;
            #pragma unroll
            for (int q = 0; q < 5; q++) {
                int k = c + 3 * q;
                float w = exp2f(k2[k] * d2);
                A[k] = fmaf(mup[k], w, A[k]);
                B[k] = fmaf(sdp[k], w, B[k]);
            }
        }
    }
    #pragma unroll
    for (int mask = 8; mask <= 32; mask <<= 1) {
        #pragma unroll
        for (int k = 0; k < 15; k++) {
            A[k] += __shfl_xor(A[k], mask, 64);
            B[k] += __shfl_xor(B[k], mask, 64);
        }
    }
    int lane = tid & 63, wv = tid >> 6;
    if (lane < 8) {
        #pragma unroll
        for (int k = 0; k < 15; k++) { red2[wv][lane][k] = A[k]; red2[wv][lane][15 + k] = B[k]; }
    }
    __syncthreads();
    if (tid < 240) {
        int t2 = tid / 30, v = tid % 30;
        AB[t2][v] = red2[0][t2][v] + red2[1][t2][v] + red2[2][t2][v] + red2[3][t2][v];
    }
    __syncthreads();
    if (tid < 192) {
        int t2 = tid / 24;
        int rem = tid % 24;
        int s = rem / 6, j = rem % 6;
        int tg = tt + t2;
        if (tg < ntar) {
            float val = lob[j];
            const float* ep = eps + ((size_t)s * nb + b) * 15;
            #pragma unroll
            for (int k = 0; k < 15; k++) {
                float h = fmaf(ep[k], AB[t2][15 + k], AB[t2][k]);
                val = fmaf(h, loW[k * 6 + j], val);
            }
            if (j >= 3) val = fmaxf(val, 0.0f) + log1pf(__expf(-fabsf(val)));  // softplus
            out[(((size_t)s * nb + b) * ntar + tg) * 6 + j] = val;
        }
    }
}

// =====================================================================
// Fallback path (generic shapes)
// =====================================================================

__global__ __launch_bounds__(1024) void enc_kernel_g(
    const float* __restrict__ x, const float* __restrict__ y,
    const float* __restrict__ xg, const float* __restrict__ enc_sigma,
    const float* __restrict__ gW, const float* __restrict__ gb,
    float* __restrict__ rep_s, int nb, int npts, int M)
{
    __shared__ float sx[6144];
    __shared__ float sy[6144];
    __shared__ float red[16][8][6];
    __shared__ float tot[8][6];
    int b = blockIdx.y;
    int mt = blockIdx.x * 8;
    int tid = threadIdx.x;
    int n3 = npts * 3;
    if (n3 > 6144) n3 = 6144;
    for (int i = tid; i < n3; i += 1024) {
        sx[i] = x[(size_t)b * npts * 3 + i];
        sy[i] = y[(size_t)b * npts * 3 + i];
    }
    int npts_l = n3 / 3;
    int mi = tid & 7, ng = tid >> 3;
    int m = mt + mi;
    bool mv = (m < M);
    float e1[3], g[3];
    for (int c = 0; c < 3; c++) {
        float inv = 1.0f / (__expf(enc_sigma[c]) + EPSF);
        e1[c] = -0.5f * inv * inv;
    }
    for (int c = 0; c < 3; c++) g[c] = mv ? xg[(size_t)(b * M + m) * 3 + c] : 0.0f;
    __syncthreads();
    float h0[3] = {0,0,0}, h1[3] = {0,0,0};
    for (int n = ng; n < npts_l; n += 128) {
        for (int c = 0; c < 3; c++) {
            float d = sx[n * 3 + c] - g[c];
            float w = __expf(e1[c] * d * d);
            h0[c] += w;
            h1[c] = fmaf(sy[n * 3 + c], w, h1[c]);
        }
    }
    for (int mask = 8; mask <= 32; mask <<= 1) {
        for (int c = 0; c < 3; c++) {
            h0[c] += __shfl_xor(h0[c], mask, 64);
            h1[c] += __shfl_xor(h1[c], mask, 64);
        }
    }
    int lane = tid & 63, wv = tid >> 6;
    if (lane < 8) {
        for (int c = 0; c < 3; c++) { red[wv][lane][c] = h0[c]; red[wv][lane][3 + c] = h1[c]; }
    }
    __syncthreads();
    if (tid < 48) {
        int mi2 = tid & 7, c2 = tid >> 3;
        float s = 0.0f;
        for (int k = 0; k < 16; k++) s += red[k][mi2][c2];
        tot[mi2][c2] = s;
    }
    __syncthreads();
    if (tid < 128) {
        int mi2 = tid & 7, j = tid >> 3;
        int m2 = mt + mi2;
        if (m2 < M) {
            float cat[6];
            for (int c = 0; c < 3; c++) {
                cat[c] = tot[mi2][c];
                cat[3 + c] = tot[mi2][3 + c] / (tot[mi2][c] + EPSF);
            }
            float r = gb[j];
            for (int i = 0; i < 6; i++) r = fmaf(cat[i], gW[i * 16 + j], r);
            rep_s[((size_t)b * 16 + j) * M + m2] = sigmoidf_(r);
        }
    }
}

__global__ __launch_bounds__(256) void rho_kernel_g(
    const float* __restrict__ rep_s,
    const float* __restrict__ w1, const float* __restrict__ b1,
    const float* __restrict__ w2, const float* __restrict__ b2,
    const float* __restrict__ w3, const float* __restrict__ b3,
    const float* __restrict__ linW, const float* __restrict__ linb,
    float* __restrict__ mu, float* __restrict__ stdv,
    int nb, int M)
{
    __shared__ float sWA[5152];
    __shared__ float sWB[5152];
    __shared__ float sIn[16][20];
    __shared__ float sH1[32][16];
    __shared__ float sH2[32][12];
    __shared__ float sH3[32][8];
    int b = blockIdx.y;
    int t0 = blockIdx.x * 8;
    int tid = threadIdx.x;
    {
        const float4* w1v = (const float4*)w1;
        const float4* w2v = (const float4*)w2;
        for (int i4 = tid; i4 < 640; i4 += 256) {
            float4 v = w1v[i4];
            float vv[4] = {v.x, v.y, v.z, v.w};
            for (int j = 0; j < 4; j++) {
                int e = 4 * i4 + j;
                sWA[(e / 80) * 81 + e % 80] = vv[j];
            }
        }
        for (int i4 = tid; i4 < 1280; i4 += 256) {
            float4 v = w2v[i4];
            float vv[4] = {v.x, v.y, v.z, v.w};
            for (int j = 0; j < 4; j++) {
                int e = 4 * i4 + j;
                sWB[(e / 160) * 161 + e % 160] = vv[j];
            }
        }
        for (int idx = tid; idx < 16 * 20; idx += 256) {
            int i = idx / 20, q = idx % 20;
            int mg = t0 - 6 + q;
            sIn[i][q] = (mg >= 0 && mg < M) ? rep_s[((size_t)b * 16 + i) * M + mg] : 0.0f;
        }
    }
    __syncthreads();
    int o = tid >> 3, q0 = tid & 7;
    {
        float a0 = b1[o], a1 = a0;
        #pragma unroll 2
        for (int i = 0; i < 16; i++) {
            const float* wp = sWA + o * 81 + i * 5;
            float u0 = wp[0], u1 = wp[1], u2 = wp[2], u3 = wp[3], u4 = wp[4];
            const float* ip = &sIn[i][0];
            a0 = fmaf(ip[q0], u0, a0);      a0 = fmaf(ip[q0+1], u1, a0);
            a0 = fmaf(ip[q0+2], u2, a0);    a0 = fmaf(ip[q0+3], u3, a0);
            a0 = fmaf(ip[q0+4], u4, a0);
            a1 = fmaf(ip[q0+8], u0, a1);    a1 = fmaf(ip[q0+9], u1, a1);
            a1 = fmaf(ip[q0+10], u2, a1);   a1 = fmaf(ip[q0+11], u3, a1);
            a1 = fmaf(ip[q0+12], u4, a1);
        }
        int g0 = t0 - 4 + q0, g1 = g0 + 8;
        sH1[o][q0]     = (g0 >= 0 && g0 < M) ? fmaxf(a0, 0.0f) : 0.0f;
        sH1[o][q0 + 8] = (g1 >= 0 && g1 < M) ? fmaxf(a1, 0.0f) : 0.0f;
    }
    __syncthreads();
    float4 wreg[5];
    {
        const float4* w3v = (const float4*)w3;
        for (int h = 0; h < 5; h++) wreg[h] = w3v[tid + 256 * h];
    }
    {
        float a0 = b2[o], a1 = a0;
        bool second = (q0 < 4);
        #pragma unroll 2
        for (int i = 0; i < 32; i++) {
            const float* wp = sWB + o * 161 + i * 5;
            float u0 = wp[0], u1 = wp[1], u2 = wp[2], u3 = wp[3], u4 = wp[4];
            const float* ip = &sH1[i][0];
            a0 = fmaf(ip[q0], u0, a0);      a0 = fmaf(ip[q0+1], u1, a0);
            a0 = fmaf(ip[q0+2], u2, a0);    a0 = fmaf(ip[q0+3], u3, a0);
            a0 = fmaf(ip[q0+4], u4, a0);
            if (second) {
                a1 = fmaf(ip[q0+8], u0, a1);    a1 = fmaf(ip[q0+9], u1, a1);
                a1 = fmaf(ip[q0+10], u2, a1);   a1 = fmaf(ip[q0+11], u3, a1);
                a1 = fmaf(ip[q0+12], u4, a1);
            }
        }
        int g0 = t0 - 2 + q0, g1 = g0 + 8;
        sH2[o][q0] = (g0 >= 0 && g0 < M) ? fmaxf(a0, 0.0f) : 0.0f;
        if (second) sH2[o][q0 + 8] = (g1 >= 0 && g1 < M) ? fmaxf(a1, 0.0f) : 0.0f;
    }
    __syncthreads();
    for (int h = 0; h < 5; h++) {
        float vv[4] = {wreg[h].x, wreg[h].y, wreg[h].z, wreg[h].w};
        for (int j = 0; j < 4; j++) {
            int e = 4 * (tid + 256 * h) + j;
            sWA[(e / 160) * 161 + e % 160] = vv[j];
        }
    }
    __syncthreads();
    {
        float a0 = b3[o];
        #pragma unroll 2
        for (int i = 0; i < 32; i++) {
            const float* wp = sWA + o * 161 + i * 5;
            float u0 = wp[0], u1 = wp[1], u2 = wp[2], u3 = wp[3], u4 = wp[4];
            const float* ip = &sH2[i][0];
            a0 = fmaf(ip[q0], u0, a0);      a0 = fmaf(ip[q0+1], u1, a0);
            a0 = fmaf(ip[q0+2], u2, a0);    a0 = fmaf(ip[q0+3], u3, a0);
            a0 = fmaf(ip[q0+4], u4, a0);
        }
        sH3[o][q0] = a0;
    }
    __syncthreads();
    if (tid < 240) {
        int q = tid / 30, j = tid % 30;
        int m = t0 + q;
        if (m < M) {
            float v = linb[j];
            #pragma unroll 8
            for (int oo = 0; oo < 32; oo++) v = fmaf(sH3[oo][q], linW[oo * 30 + j], v);
            if (j < 15) mu[((size_t)b * M + m) * 16 + j] = v;
            else        stdv[((size_t)b * M + m) * 16 + (j - 15)] = 0.1f + 0.9f * sigmoidf_(v);
        }
    }
}

extern "C" void kernel_launch(void* const* d_in, const int* in_sizes, int n_in,
                              void* d_out, int out_size, void* d_ws, size_t ws_size,
                              hipStream_t stream)
{
    const float* x         = (const float*)d_in[0];
    const float* y         = (const float*)d_in[1];
    const float* x_out     = (const float*)d_in[2];
    const float* x_grid    = (const float*)d_in[3];
    const float* eps_noise = (const float*)d_in[4];
    const float* enc_sigma = (const float*)d_in[5];
    const float* gW        = (const float*)d_in[6];
    const float* gb        = (const float*)d_in[7];
    const float* w1        = (const float*)d_in[8];
    const float* b1        = (const float*)d_in[9];
    const float* w2        = (const float*)d_in[10];
    const float* b2        = (const float*)d_in[11];
    const float* w3        = (const float*)d_in[12];
    const float* b3        = (const float*)d_in[13];
    const float* linW      = (const float*)d_in[14];
    const float* linb      = (const float*)d_in[15];
    const float* int_sigma = (const float*)d_in[16];
    const float* loW       = (const float*)d_in[17];
    const float* lob       = (const float*)d_in[18];
    float* out = (float*)d_out;

    const int NS = 4, C = 3, NBASIS = 5;
    int nb   = in_sizes[4] / (NS * C * NBASIS);       // eps_noise: (NS, nb, 15)
    int npts = in_sizes[0] / (nb * C);
    int ntar = in_sizes[2] / (nb * C);
    int M    = in_sizes[3] / (nb * C);

    float* mu   = (float*)d_ws;                        // (nb, M, 16)
    float* stdv = mu + (size_t)nb * M * 16;            // (nb, M, 16)

    bool fast = (npts == 2048 && M <= 320);
    if (fast) {
        encrho_kernel<<<dim3(16, nb), 512, 0, stream>>>(
            x, y, x_grid, enc_sigma, gW, gb,
            w1, b1, w2, b2, w3, b3, linW, linb, mu, stdv, nb, M);
    } else {
        float* rep_s = stdv + (size_t)nb * M * 16;     // (nb, 16, M)
        enc_kernel_g<<<dim3((M + 7) / 8, nb), 1024, 0, stream>>>(
            x, y, x_grid, enc_sigma, gW, gb, rep_s, nb, npts, M);
        rho_kernel_g<<<dim3((M + 7) / 8, nb), 256, 0, stream>>>(
            rep_s, w1, b1, w2, b2, w3, b3, linW, linb, mu, stdv, nb, M);
    }
    final_kernel<<<dim3((ntar + 7) / 8, nb), 256, 0, stream>>>(
        x_out, x_grid, int_sigma, eps_noise, mu, stdv, loW, lob, out, nb, ntar, M);
}

// Round 15
// 37.208 us; speedup vs baseline: 1.2145x; 1.0125x over previous
//
#include <hip/hip_runtime.h>
#include <math.h>

#define EPSF 1e-6f
#define LOG2E 1.4426950408889634f
#define NSIG 5.0f

__device__ __forceinline__ float sigmoidf_(float v) { return 1.0f / (1.0f + __expf(-v)); }

// =====================================================================
// K1: fused enc + rho per 20-col tile, Gaussian-support prefilter.
// grid (16, nb), 512 threads. LDS UNION (Phase A flt overlays Phase B
// weight/tile regions) -> 59.4 KB. (R9/R14 configuration — best measured.)
// =====================================================================
__global__ __launch_bounds__(512, 1) void encrho_kernel(
    const float* __restrict__ x, const float* __restrict__ y,
    const float* __restrict__ xg, const float* __restrict__ enc_sigma,
    const float* __restrict__ gW, const float* __restrict__ gb,
    const float* __restrict__ w1, const float* __restrict__ b1,
    const float* __restrict__ w2, const float* __restrict__ b2,
    const float* __restrict__ w3, const float* __restrict__ b3,
    const float* __restrict__ linW, const float* __restrict__ linb,
    float* __restrict__ mu, float* __restrict__ stdv,
    int nb, int M)
{
    __shared__ __align__(16) float smem[14856];
    float* sWA = smem;
    float* sWB = smem + 5152;
    float* sH1 = smem + 10304;
    float* sH2 = smem + 11200;
    float* sH3 = smem + 11968;
    float* sIn = smem + 12608;
    float* flt = smem;               // [3][2048] float2 (Phase A only)
    float* red = smem + 13120;
    float* tot = smem + 14656;
    float* sRange = smem + 14848;
    __shared__ int scnt[3];
    __shared__ int spad[3];

    const int tid = threadIdx.x;
    const int b = blockIdx.y;
    const int c0 = blockIdx.x * 20;
    const int ic = tid & 31, ng = tid >> 5;

    // ---------------- Phase A: filtered encoder over 32 cols ----------------
    {
        float sg0 = __expf(enc_sigma[0]) + EPSF;
        float sg1 = __expf(enc_sigma[1]) + EPSF;
        float sg2 = __expf(enc_sigma[2]) + EPSF;
        float e20 = -0.5f * LOG2E / (sg0 * sg0);
        float e21 = -0.5f * LOG2E / (sg1 * sg1);
        float e22 = -0.5f * LOG2E / (sg2 * sg2);

        int mg = c0 - 6 + ic;
        bool cv = (mg >= 0 && mg < M);
        float g0 = 0, g1 = 0, g2 = 0;
        if (cv) {
            const float* gp = xg + (size_t)(b * M + mg) * 3;
            g0 = gp[0]; g1 = gp[1]; g2 = gp[2];
        }
        if (tid < 3) scnt[tid] = 0;
        if (tid < 96) {
            int c = tid >> 5;
            int col = c0 - 6 + ic;
            col = col < 0 ? 0 : (col >= M ? M - 1 : col);
            float gv = xg[(size_t)(b * M + col) * 3 + c];
            float gmn = gv, gmx = gv;
            #pragma unroll
            for (int mask = 1; mask <= 16; mask <<= 1) {
                gmn = fminf(gmn, __shfl_xor(gmn, mask, 64));
                gmx = fmaxf(gmx, __shfl_xor(gmx, mask, 64));
            }
            if (ic == 0) {
                float sgc = __expf(enc_sigma[c]) + EPSF;
                sRange[c] = gmn - NSIG * sgc;
                sRange[3 + c] = gmx + NSIG * sgc;
            }
        }
        __syncthreads();
        // filter pass
        {
            const float* xb = x + (size_t)b * 6144;
            const float* yb = y + (size_t)b * 6144;
            #pragma unroll 1
            for (int idx = tid; idx < 6144; idx += 512) {
                float xv = xb[idx];
                int c = idx % 3;
                if (xv >= sRange[c] && xv <= sRange[3 + c]) {
                    int p = atomicAdd(&scnt[c], 1);
                    int o = (c << 12) + (p << 1);
                    flt[o] = xv;
                    flt[o + 1] = yb[idx];
                }
            }
        }
        __syncthreads();
        if (tid < 3) spad[tid] = (scnt[tid] + 31) & ~31;
        __syncthreads();
        #pragma unroll
        for (int c = 0; c < 3; c++) {
            int cnt = scnt[c], cp = spad[c];
            for (int p = cnt + tid; p < cp; p += 512) {
                int o = (c << 12) + (p << 1);
                flt[o] = 1e30f;
                flt[o + 1] = 0.0f;
            }
        }
        __syncthreads();
        // main loops: per channel, dual accumulator pairs (n, n+16)
        float h[6];
        {
            const float2* f = (const float2*)flt;
            int cp = spad[0];
            float s0a = 0, s0b = 0, s1a = 0, s1b = 0;
            #pragma unroll 2
            for (int n = ng; n < cp; n += 32) {
                float2 va = f[n], vb = f[n + 16];
                float da = va.x - g0; float wa = exp2f(e20 * da * da);
                float db = vb.x - g0; float wb = exp2f(e20 * db * db);
                s0a += wa; s1a = fmaf(va.y, wa, s1a);
                s0b += wb; s1b = fmaf(vb.y, wb, s1b);
            }
            h[0] = s0a + s0b; h[3] = s1a + s1b;
        }
        {
            const float2* f = (const float2*)flt + 2048;
            int cp = spad[1];
            float s0a = 0, s0b = 0, s1a = 0, s1b = 0;
            #pragma unroll 2
            for (int n = ng; n < cp; n += 32) {
                float2 va = f[n], vb = f[n + 16];
                float da = va.x - g1; float wa = exp2f(e21 * da * da);
                float db = vb.x - g1; float wb = exp2f(e21 * db * db);
                s0a += wa; s1a = fmaf(va.y, wa, s1a);
                s0b += wb; s1b = fmaf(vb.y, wb, s1b);
            }
            h[1] = s0a + s0b; h[4] = s1a + s1b;
        }
        {
            const float2* f = (const float2*)flt + 4096;
            int cp = spad[2];
            float s0a = 0, s0b = 0, s1a = 0, s1b = 0;
            #pragma unroll 2
            for (int n = ng; n < cp; n += 32) {
                float2 va = f[n], vb = f[n + 16];
                float da = va.x - g2; float wa = exp2f(e22 * da * da);
                float db = vb.x - g2; float wb = exp2f(e22 * db * db);
                s0a += wa; s1a = fmaf(va.y, wa, s1a);
                s0b += wb; s1b = fmaf(vb.y, wb, s1b);
            }
            h[2] = s0a + s0b; h[5] = s1a + s1b;
        }
        __syncthreads();   // all flt reads done; sWA/sWB region reusable
        #pragma unroll
        for (int c = 0; c < 6; c++) h[c] += __shfl_xor(h[c], 32, 64);
        int lane = tid & 63, wv = tid >> 6;
        if (lane < 32) {
            float* rp = red + wv * 192 + lane * 6;
            #pragma unroll
            for (int c = 0; c < 6; c++) rp[c] = h[c];
        }
        // stage w1 (pad 81) and w2 (pad 161) into freed flt region
        {
            const float4* w1v4 = (const float4*)w1;   // 640
            const float4* w2v4 = (const float4*)w2;   // 1280
            #pragma unroll 1
            for (int i4 = tid; i4 < 640; i4 += 512) {
                float4 v = w1v4[i4];
                float vv[4] = {v.x, v.y, v.z, v.w};
                #pragma unroll
                for (int j = 0; j < 4; j++) {
                    int e = 4 * i4 + j;
                    sWA[(e / 80) * 81 + e % 80] = vv[j];
                }
            }
            #pragma unroll 1
            for (int i4 = tid; i4 < 1280; i4 += 512) {
                float4 v = w2v4[i4];
                float vv[4] = {v.x, v.y, v.z, v.w};
                #pragma unroll
                for (int j = 0; j < 4; j++) {
                    int e = 4 * i4 + j;
                    sWB[(e / 160) * 161 + e % 160] = vv[j];
                }
            }
        }
        __syncthreads();
        if (tid < 192) {
            int ic2 = tid & 31, c = tid >> 5;
            float s = 0.0f;
            #pragma unroll
            for (int w = 0; w < 8; w++) s += red[w * 192 + ic2 * 6 + c];
            tot[ic2 * 6 + c] = s;
        }
        __syncthreads();
        {
            int j = tid >> 5, ic2 = tid & 31;
            int mg2 = c0 - 6 + ic2;
            float v = 0.0f;
            if (mg2 >= 0 && mg2 < M) {
                const float* tp = tot + ic2 * 6;
                float cat[6];
                #pragma unroll
                for (int c = 0; c < 3; c++) {
                    cat[c] = tp[c];
                    cat[3 + c] = tp[3 + c] / (tp[c] + EPSF);
                }
                float r = gb[j];
                #pragma unroll
                for (int i = 0; i < 6; i++) r = fmaf(cat[i], gW[i * 16 + j], r);
                v = sigmoidf_(r);
            }
            sIn[j * 32 + ic2] = v;
        }
    }
    __syncthreads();

    // ---------------- Phase B: rho CNN + head ----------------
    {
        int o = tid >> 4, q0 = tid & 15;
        {
            float a0 = b1[o], a1 = a0;
            bool two = (q0 < 12);
            #pragma unroll 2
            for (int i = 0; i < 16; i++) {
                const float* wp = sWA + o * 81 + i * 5;
                float u0 = wp[0], u1 = wp[1], u2 = wp[2], u3 = wp[3], u4 = wp[4];
                const float* ip = sIn + i * 32;
                a0 = fmaf(ip[q0], u0, a0);     a0 = fmaf(ip[q0+1], u1, a0);
                a0 = fmaf(ip[q0+2], u2, a0);   a0 = fmaf(ip[q0+3], u3, a0);
                a0 = fmaf(ip[q0+4], u4, a0);
                if (two) {
                    a1 = fmaf(ip[q0+16], u0, a1);  a1 = fmaf(ip[q0+17], u1, a1);
                    a1 = fmaf(ip[q0+18], u2, a1);  a1 = fmaf(ip[q0+19], u3, a1);
                    a1 = fmaf(ip[q0+20], u4, a1);
                }
            }
            int g0c = c0 - 4 + q0, g1c = g0c + 16;
            sH1[o * 28 + q0] = (g0c >= 0 && g0c < M) ? fmaxf(a0, 0.0f) : 0.0f;
            if (two) sH1[o * 28 + q0 + 16] = (g1c >= 0 && g1c < M) ? fmaxf(a1, 0.0f) : 0.0f;
        }
        __syncthreads();
        float4 wreg0, wreg1, wreg2;
        {
            const float4* w3v = (const float4*)w3;   // 1280
            wreg0 = w3v[tid];
            wreg1 = w3v[tid + 512];
            if (tid < 256) wreg2 = w3v[tid + 1024];
        }
        {
            float a0 = b2[o], a1 = a0;
            bool two = (q0 < 8);
            #pragma unroll 2
            for (int i = 0; i < 32; i++) {
                const float* wp = sWB + o * 161 + i * 5;
                float u0 = wp[0], u1 = wp[1], u2 = wp[2], u3 = wp[3], u4 = wp[4];
                const float* ip = sH1 + i * 28;
                a0 = fmaf(ip[q0], u0, a0);     a0 = fmaf(ip[q0+1], u1, a0);
                a0 = fmaf(ip[q0+2], u2, a0);   a0 = fmaf(ip[q0+3], u3, a0);
                a0 = fmaf(ip[q0+4], u4, a0);
                if (two) {
                    a1 = fmaf(ip[q0+16], u0, a1);  a1 = fmaf(ip[q0+17], u1, a1);
                    a1 = fmaf(ip[q0+18], u2, a1);  a1 = fmaf(ip[q0+19], u3, a1);
                    a1 = fmaf(ip[q0+20], u4, a1);
                }
            }
            int g0c = c0 - 2 + q0, g1c = g0c + 16;
            sH2[o * 24 + q0] = (g0c >= 0 && g0c < M) ? fmaxf(a0, 0.0f) : 0.0f;
            if (two) sH2[o * 24 + q0 + 16] = (g1c >= 0 && g1c < M) ? fmaxf(a1, 0.0f) : 0.0f;
        }
        __syncthreads();   // conv2 done reading sWB; sWA (conv1 w1) also dead
        {
            float vv0[4] = {wreg0.x, wreg0.y, wreg0.z, wreg0.w};
            #pragma unroll
            for (int j = 0; j < 4; j++) {
                int e = 4 * tid + j;
                sWA[(e / 160) * 161 + e % 160] = vv0[j];
            }
            float vv1[4] = {wreg1.x, wreg1.y, wreg1.z, wreg1.w};
            #pragma unroll
            for (int j = 0; j < 4; j++) {
                int e = 4 * (tid + 512) + j;
                sWA[(e / 160) * 161 + e % 160] = vv1[j];
            }
            if (tid < 256) {
                float vv2[4] = {wreg2.x, wreg2.y, wreg2.z, wreg2.w};
                #pragma unroll
                for (int j = 0; j < 4; j++) {
                    int e = 4 * (tid + 1024) + j;
                    sWA[(e / 160) * 161 + e % 160] = vv2[j];
                }
            }
        }
        __syncthreads();
        {
            float a0 = b3[o], a1 = a0;
            bool two = (q0 < 4);
            #pragma unroll 2
            for (int i = 0; i < 32; i++) {
                const float* wp = sWA + o * 161 + i * 5;
                float u0 = wp[0], u1 = wp[1], u2 = wp[2], u3 = wp[3], u4 = wp[4];
                const float* ip = sH2 + i * 24;
                a0 = fmaf(ip[q0], u0, a0);     a0 = fmaf(ip[q0+1], u1, a0);
                a0 = fmaf(ip[q0+2], u2, a0);   a0 = fmaf(ip[q0+3], u3, a0);
                a0 = fmaf(ip[q0+4], u4, a0);
                if (two) {
                    a1 = fmaf(ip[q0+16], u0, a1);  a1 = fmaf(ip[q0+17], u1, a1);
                    a1 = fmaf(ip[q0+18], u2, a1);  a1 = fmaf(ip[q0+19], u3, a1);
                    a1 = fmaf(ip[q0+20], u4, a1);
                }
            }
            sH3[o * 20 + q0] = a0;
            if (two) sH3[o * 20 + q0 + 16] = a1;
        }
        __syncthreads();
        #pragma unroll 1
        for (int idx = tid; idx < 600; idx += 512) {
            int q = idx / 30, j = idx % 30;
            int m = c0 + q;
            if (m < M) {
                float v = linb[j];
                #pragma unroll 8
                for (int oo = 0; oo < 32; oo++) v = fmaf(sH3[oo * 20 + q], linW[oo * 30 + j], v);
                if (j < 15) mu[((size_t)b * M + m) * 16 + j] = v;
                else        stdv[((size_t)b * M + m) * 16 + (j - 15)] = 0.1f + 0.9f * sigmoidf_(v);
            }
        }
    }
}

// ---------------- K2: windowed interpolation + output head ----------------
__global__ __launch_bounds__(256, 4) void final_kernel(
    const float* __restrict__ x_out, const float* __restrict__ xg,
    const float* __restrict__ int_sigma, const float* __restrict__ eps,
    const float* __restrict__ mu, const float* __restrict__ stdv,
    const float* __restrict__ loW, const float* __restrict__ lob,
    float* __restrict__ out, int nb, int ntar, int M)
{
    __shared__ float red2[4][8][30];
    __shared__ float AB[8][30];
    int b = blockIdx.y;
    int tt = blockIdx.x * 8;
    int tid = threadIdx.x;
    int ti = tid & 7, mg = tid >> 3;
    int t = tt + ti;
    bool tv = (t < ntar);
    float xt[3];
    for (int c = 0; c < 3; c++) xt[c] = tv ? x_out[((size_t)b * ntar + t) * 3 + c] : 0.0f;
    float k2[15], Wc[3] = {0, 0, 0};
    #pragma unroll
    for (int k = 0; k < 15; k++) {
        float isc = __expf(int_sigma[k]) + EPSF;
        k2[k] = -0.5f * LOG2E / (isc * isc);
        Wc[k % 3] = fmaxf(Wc[k % 3], NSIG * isc);
    }
    float gg0 = xg[(size_t)b * M * 3];
    float ggL = xg[((size_t)b * M + (M - 1)) * 3];
    float Dx = (ggL - gg0) / (float)(M - 1);
    float invDx = 1.0f / Dx;
    float A[15], B[15];
    #pragma unroll
    for (int k = 0; k < 15; k++) { A[k] = 0.0f; B[k] = 0.0f; }
    #pragma unroll
    for (int c = 0; c < 3; c++) {
        float xtc = xt[c];
        int lo = (int)floorf((xtc - Wc[c] - gg0) * invDx) - 1;
        int hi = (int)ceilf((xtc + Wc[c] - gg0) * invDx) + 1;
        lo = lo < 0 ? 0 : lo;
        hi = hi > M - 1 ? M - 1 : hi;
        #pragma unroll 1
        for (int m = lo + mg; m <= hi; m += 32) {
            float d = (gg0 + m * Dx) - xtc;
            float d2 = d * d;
            const float* mup = mu + ((size_t)b * M + m) * 16;
            const float* sdp = stdv + ((size_t)b * M + m) * 16;
            #pragma unroll
            for (int q = 0; q < 5; q++) {
                int k = c + 3 * q;
                float w = exp2f(k2[k] * d2);
                A[k] = fmaf(mup[k], w, A[k]);
                B[k] = fmaf(sdp[k], w, B[k]);
            }
        }
    }
    #pragma unroll
    for (int mask = 8; mask <= 32; mask <<= 1) {
        #pragma unroll
        for (int k = 0; k < 15; k++) {
            A[k] += __shfl_xor(A[k], mask, 64);
            B[k] += __shfl_xor(B[k], mask, 64);
        }
    }
    int lane = tid & 63, wv = tid >> 6;
    if (lane < 8) {
        #pragma unroll
        for (int k = 0; k < 15; k++) { red2[wv][lane][k] = A[k]; red2[wv][lane][15 + k] = B[k]; }
    }
    __syncthreads();
    if (tid < 240) {
        int t2 = tid / 30, v = tid % 30;
        AB[t2][v] = red2[0][t2][v] + red2[1][t2][v] + red2[2][t2][v] + red2[3][t2][v];
    }
    __syncthreads();
    if (tid < 192) {
        int t2 = tid / 24;
        int rem = tid % 24;
        int s = rem / 6, j = rem % 6;
        int tg = tt + t2;
        if (tg < ntar) {
            float val = lob[j];
            const float* ep = eps + ((size_t)s * nb + b) * 15;
            #pragma unroll
            for (int k = 0; k < 15; k++) {
                float h = fmaf(ep[k], AB[t2][15 + k], AB[t2][k]);
                val = fmaf(h, loW[k * 6 + j], val);
            }
            if (j >= 3) val = fmaxf(val, 0.0f) + log1pf(__expf(-fabsf(val)));  // softplus
            out[(((size_t)s * nb + b) * ntar + tg) * 6 + j] = val;
        }
    }
}

// =====================================================================
// Fallback path (generic shapes)
// =====================================================================

__global__ __launch_bounds__(1024) void enc_kernel_g(
    const float* __restrict__ x, const float* __restrict__ y,
    const float* __restrict__ xg, const float* __restrict__ enc_sigma,
    const float* __restrict__ gW, const float* __restrict__ gb,
    float* __restrict__ rep_s, int nb, int npts, int M)
{
    __shared__ float sx[6144];
    __shared__ float sy[6144];
    __shared__ float red[16][8][6];
    __shared__ float tot[8][6];
    int b = blockIdx.y;
    int mt = blockIdx.x * 8;
    int tid = threadIdx.x;
    int n3 = npts * 3;
    if (n3 > 6144) n3 = 6144;
    for (int i = tid; i < n3; i += 1024) {
        sx[i] = x[(size_t)b * npts * 3 + i];
        sy[i] = y[(size_t)b * npts * 3 + i];
    }
    int npts_l = n3 / 3;
    int mi = tid & 7, ng = tid >> 3;
    int m = mt + mi;
    bool mv = (m < M);
    float e1[3], g[3];
    for (int c = 0; c < 3; c++) {
        float inv = 1.0f / (__expf(enc_sigma[c]) + EPSF);
        e1[c] = -0.5f * inv * inv;
    }
    for (int c = 0; c < 3; c++) g[c] = mv ? xg[(size_t)(b * M + m) * 3 + c] : 0.0f;
    __syncthreads();
    float h0[3] = {0,0,0}, h1[3] = {0,0,0};
    for (int n = ng; n < npts_l; n += 128) {
        for (int c = 0; c < 3; c++) {
            float d = sx[n * 3 + c] - g[c];
            float w = __expf(e1[c] * d * d);
            h0[c] += w;
            h1[c] = fmaf(sy[n * 3 + c], w, h1[c]);
        }
    }
    for (int mask = 8; mask <= 32; mask <<= 1) {
        for (int c = 0; c < 3; c++) {
            h0[c] += __shfl_xor(h0[c], mask, 64);
            h1[c] += __shfl_xor(h1[c], mask, 64);
        }
    }
    int lane = tid & 63, wv = tid >> 6;
    if (lane < 8) {
        for (int c = 0; c < 3; c++) { red[wv][lane][c] = h0[c]; red[wv][lane][3 + c] = h1[c]; }
    }
    __syncthreads();
    if (tid < 48) {
        int mi2 = tid & 7, c2 = tid >> 3;
        float s = 0.0f;
        for (int k = 0; k < 16; k++) s += red[k][mi2][c2];
        tot[mi2][c2] = s;
    }
    __syncthreads();
    if (tid < 128) {
        int mi2 = tid & 7, j = tid >> 3;
        int m2 = mt + mi2;
        if (m2 < M) {
            float cat[6];
            for (int c = 0; c < 3; c++) {
                cat[c] = tot[mi2][c];
                cat[3 + c] = tot[mi2][3 + c] / (tot[mi2][c] + EPSF);
            }
            float r = gb[j];
            for (int i = 0; i < 6; i++) r = fmaf(cat[i], gW[i * 16 + j], r);
            rep_s[((size_t)b * 16 + j) * M + m2] = sigmoidf_(r);
        }
    }
}

__global__ __launch_bounds__(256) void rho_kernel_g(
    const float* __restrict__ rep_s,
    const float* __restrict__ w1, const float* __restrict__ b1,
    const float* __restrict__ w2, const float* __restrict__ b2,
    const float* __restrict__ w3, const float* __restrict__ b3,
    const float* __restrict__ linW, const float* __restrict__ linb,
    float* __restrict__ mu, float* __restrict__ stdv,
    int nb, int M)
{
    __shared__ float sWA[5152];
    __shared__ float sWB[5152];
    __shared__ float sIn[16][20];
    __shared__ float sH1[32][16];
    __shared__ float sH2[32][12];
    __shared__ float sH3[32][8];
    int b = blockIdx.y;
    int t0 = blockIdx.x * 8;
    int tid = threadIdx.x;
    {
        const float4* w1v = (const float4*)w1;
        const float4* w2v = (const float4*)w2;
        for (int i4 = tid; i4 < 640; i4 += 256) {
            float4 v = w1v[i4];
            float vv[4] = {v.x, v.y, v.z, v.w};
            for (int j = 0; j < 4; j++) {
                int e = 4 * i4 + j;
                sWA[(e / 80) * 81 + e % 80] = vv[j];
            }
        }
        for (int i4 = tid; i4 < 1280; i4 += 256) {
            float4 v = w2v[i4];
            float vv[4] = {v.x, v.y, v.z, v.w};
            for (int j = 0; j < 4; j++) {
                int e = 4 * i4 + j;
                sWB[(e / 160) * 161 + e % 160] = vv[j];
            }
        }
        for (int idx = tid; idx < 16 * 20; idx += 256) {
            int i = idx / 20, q = idx % 20;
            int mg = t0 - 6 + q;
            sIn[i][q] = (mg >= 0 && mg < M) ? rep_s[((size_t)b * 16 + i) * M + mg] : 0.0f;
        }
    }
    __syncthreads();
    int o = tid >> 3, q0 = tid & 7;
    {
        float a0 = b1[o], a1 = a0;
        #pragma unroll 2
        for (int i = 0; i < 16; i++) {
            const float* wp = sWA + o * 81 + i * 5;
            float u0 = wp[0], u1 = wp[1], u2 = wp[2], u3 = wp[3], u4 = wp[4];
            const float* ip = &sIn[i][0];
            a0 = fmaf(ip[q0], u0, a0);      a0 = fmaf(ip[q0+1], u1, a0);
            a0 = fmaf(ip[q0+2], u2, a0);    a0 = fmaf(ip[q0+3], u3, a0);
            a0 = fmaf(ip[q0+4], u4, a0);
            a1 = fmaf(ip[q0+8], u0, a1);    a1 = fmaf(ip[q0+9], u1, a1);
            a1 = fmaf(ip[q0+10], u2, a1);   a1 = fmaf(ip[q0+11], u3, a1);
            a1 = fmaf(ip[q0+12], u4, a1);
        }
        int g0 = t0 - 4 + q0, g1 = g0 + 8;
        sH1[o][q0]     = (g0 >= 0 && g0 < M) ? fmaxf(a0, 0.0f) : 0.0f;
        sH1[o][q0 + 8] = (g1 >= 0 && g1 < M) ? fmaxf(a1, 0.0f) : 0.0f;
    }
    __syncthreads();
    float4 wreg[5];
    {
        const float4* w3v = (const float4*)w3;
        for (int h = 0; h < 5; h++) wreg[h] = w3v[tid + 256 * h];
    }
    {
        float a0 = b2[o], a1 = a0;
        bool second = (q0 < 4);
        #pragma unroll 2
        for (int i = 0; i < 32; i++) {
            const float* wp = sWB + o * 161 + i * 5;
            float u0 = wp[0], u1 = wp[1], u2 = wp[2], u3 = wp[3], u4 = wp[4];
            const float* ip = &sH1[i][0];
            a0 = fmaf(ip[q0], u0, a0);      a0 = fmaf(ip[q0+1], u1, a0);
            a0 = fmaf(ip[q0+2], u2, a0);    a0 = fmaf(ip[q0+3], u3, a0);
            a0 = fmaf(ip[q0+4], u4, a0);
            if (second) {
                a1 = fmaf(ip[q0+8], u0, a1);    a1 = fmaf(ip[q0+9], u1, a1);
                a1 = fmaf(ip[q0+10], u2, a1);   a1 = fmaf(ip[q0+11], u3, a1);
                a1 = fmaf(ip[q0+12], u4, a1);
            }
        }
        int g0 = t0 - 2 + q0, g1 = g0 + 8;
        sH2[o][q0] = (g0 >= 0 && g0 < M) ? fmaxf(a0, 0.0f) : 0.0f;
        if (second) sH2[o][q0 + 8] = (g1 >= 0 && g1 < M) ? fmaxf(a1, 0.0f) : 0.0f;
    }
    __syncthreads();
    for (int h = 0; h < 5; h++) {
        float vv[4] = {wreg[h].x, wreg[h].y, wreg[h].z, wreg[h].w};
        for (int j = 0; j < 4; j++) {
            int e = 4 * (tid + 256 * h) + j;
            sWA[(e / 160) * 161 + e % 160] = vv[j];
        }
    }
    __syncthreads();
    {
        float a0 = b3[o];
        #pragma unroll 2
        for (int i = 0; i < 32; i++) {
            const float* wp = sWA + o * 161 + i * 5;
            float u0 = wp[0], u1 = wp[1], u2 = wp[2], u3 = wp[3], u4 = wp[4];
            const float* ip = &sH2[i][0];
            a0 = fmaf(ip[q0], u0, a0);      a0 = fmaf(ip[q0+1], u1, a0);
            a0 = fmaf(ip[q0+2], u2, a0);    a0 = fmaf(ip[q0+3], u3, a0);
            a0 = fmaf(ip[q0+4], u4, a0);
        }
        sH3[o][q0] = a0;
    }
    __syncthreads();
    if (tid < 240) {
        int q = tid / 30, j = tid % 30;
        int m = t0 + q;
        if (m < M) {
            float v = linb[j];
            #pragma unroll 8
            for (int oo = 0; oo < 32; oo++) v = fmaf(sH3[oo][q], linW[oo * 30 + j], v);
            if (j < 15) mu[((size_t)b * M + m) * 16 + j] = v;
            else        stdv[((size_t)b * M + m) * 16 + (j - 15)] = 0.1f + 0.9f * sigmoidf_(v);
        }
    }
}

extern "C" void kernel_launch(void* const* d_in, const int* in_sizes, int n_in,
                              void* d_out, int out_size, void* d_ws, size_t ws_size,
                              hipStream_t stream)
{
    const float* x         = (const float*)d_in[0];
    const float* y         = (const float*)d_in[1];
    const float* x_out     = (const float*)d_in[2];
    const float* x_grid    = (const float*)d_in[3];
    const float* eps_noise = (const float*)d_in[4];
    const float* enc_sigma = (const float*)d_in[5];
    const float* gW        = (const float*)d_in[6];
    const float* gb        = (const float*)d_in[7];
    const float* w1        = (const float*)d_in[8];
    const float* b1        = (const float*)d_in[9];
    const float* w2        = (const float*)d_in[10];
    const float* b2        = (const float*)d_in[11];
    const float* w3        = (const float*)d_in[12];
    const float* b3        = (const float*)d_in[13];
    const float* linW      = (const float*)d_in[14];
    const float* linb      = (const float*)d_in[15];
    const float* int_sigma = (const float*)d_in[16];
    const float* loW       = (const float*)d_in[17];
    const float* lob       = (const float*)d_in[18];
    float* out = (float*)d_out;

    const int NS = 4, C = 3, NBASIS = 5;
    int nb   = in_sizes[4] / (NS * C * NBASIS);       // eps_noise: (NS, nb, 15)
    int npts = in_sizes[0] / (nb * C);
    int ntar = in_sizes[2] / (nb * C);
    int M    = in_sizes[3] / (nb * C);

    float* mu   = (float*)d_ws;                        // (nb, M, 16)
    float* stdv = mu + (size_t)nb * M * 16;            // (nb, M, 16)

    bool fast = (npts == 2048 && M <= 320);
    if (fast) {
        encrho_kernel<<<dim3(16, nb), 512, 0, stream>>>(
            x, y, x_grid, enc_sigma, gW, gb,
            w1, b1, w2, b2, w3, b3, linW, linb, mu, stdv, nb, M);
    } else {
        float* rep_s = stdv + (size_t)nb * M * 16;     // (nb, 16, M)
        enc_kernel_g<<<dim3((M + 7) / 8, nb), 1024, 0, stream>>>(
            x, y, x_grid, enc_sigma, gW, gb, rep_s, nb, npts, M);
        rho_kernel_g<<<dim3((M + 7) / 8, nb), 256, 0, stream>>>(
            rep_s, w1, b1, w2, b2, w3, b3, linW, linb, mu, stdv, nb, M);
    }
    final_kernel<<<dim3((ntar + 7) / 8, nb), 256, 0, stream>>>(
        x_out, x_grid, int_sigma, eps_noise, mu, stdv, loW, lob, out, nb, ntar, M);
}